// Round 5
// baseline (136.085 us; speedup 1.0000x reference)
//
#include <hip/hip_runtime.h>
#include <math.h>

#define Nn 65536

typedef short s16x8 __attribute__((ext_vector_type(8)));
typedef float f32x4 __attribute__((ext_vector_type(4)));
typedef unsigned int u32;

__device__ __forceinline__ unsigned short f2bf(float x) {
    u32 u = __float_as_uint(x);
    u += 0x7FFFu + ((u >> 16) & 1u);
    return (unsigned short)(u >> 16);
}

// argmax over row s of the 4x4 type_matching (first max wins, matches jnp.argmax)
__device__ __forceinline__ int best_t_for(const float* __restrict__ tm, int s, float* mOut) {
    float m = tm[s * 4];
    int am = 0;
#pragma unroll
    for (int j = 1; j < 4; ++j) {
        float v = tm[s * 4 + j];
        if (v > m) { m = v; am = j; }
    }
    if (mOut) *mOut = m;
    return am;
}

// ============ k_prepw: weight convert ONLY (96 blocks) ============
// fp32 [D][H] -> bf16 fragment-linear for the 12 live (s, best_t) matrices
__global__ void k_prepw(const float* __restrict__ tm,
                        const float* __restrict__ W1, const float* __restrict__ W2,
                        const float* __restrict__ C1, unsigned short* __restrict__ wbf) {
    int u = blockIdx.x * 256 + threadIdx.x;      // 0..24575
    int mat = u >> 11;
    int rr = u & 2047;
    int f = rr >> 6, lane = rr & 63;
    int kk = f >> 3, n8 = f & 7;
    int q = lane >> 4, l15 = lane & 15;
    int sm = mat / 3, w = mat - sm * 3;
    int t = best_t_for(tm, sm, nullptr);
    const float* src = (w == 0) ? W1 : (w == 1) ? W2 : C1;
    const float* sp = src + (((sm * 4 + t) << 14) + n8 * 16 + l15);
    int k0 = kk * 32 + q * 8;
    s16x8 o;
#pragma unroll
    for (int j = 0; j < 8; ++j) o[j] = (short)f2bf(sp[(k0 + j) * 128]);
    *(s16x8*)(wbf + (size_t)u * 8) = o;
}

// ================= k_fused: one kernel, block-local partition =================
// Each block: 64 CONSECUTIVE rows (dense coalesced read -> swizzled bf16 LDS tile).
// Wave 0 ballot-sorts the 64 rows into <=7 type-uniform 16-row segments (pad = -1).
// Per segment: gemm1 (W1,relu)->Hbuf, gemm2 (W2)->out_state, gemm3 (C1) -> classifier
// reduce -> out_score. Weights streamed per-segment from L2-resident wbf into a 2-deep
// ping-pong register buffer (static indices only). 8 waves x 16 cols; 3 barriers/block.
// No global partition kernel, no bucket gather, no cross-kernel dependency.
// A/H swizzle: row*128 + ((col + (row&15)*8) & 127)
__global__ __launch_bounds__(512, 4) void k_fused(
    const float* __restrict__ states, const float* __restrict__ scores,
    const int* __restrict__ type_ids, const float* __restrict__ tm,
    const float* __restrict__ b1g, const float* __restrict__ b2g,
    const float* __restrict__ c1g, const float* __restrict__ C2,
    const float* __restrict__ c2, const unsigned short* __restrict__ wbf,
    float* __restrict__ out_state, float* __restrict__ out_score,
    float* __restrict__ out_prob)
{
    __shared__ __align__(16) unsigned short Abuf[64 * 128];    // 16 KB
    __shared__ __align__(16) unsigned short Hbuf[112 * 128];   // 28 KB (7 segs max)
    __shared__ int permLds[112];
    __shared__ int segTypeLds[8];
    __shared__ int Gs;
    __shared__ float scoreLds[64];
    __shared__ float pLds[8][112];                             // 3.5 KB
    __shared__ float c2sL[4];

    const int t = threadIdx.x;
    const int gid0 = blockIdx.x * 64;
    const int lane = t & 63;
    const int wv = t >> 6;            // wave 0..7 -> 16-col slice
    const int l15 = lane & 15;
    const int quad = lane >> 4;
    const int myRow = t >> 3;         // staging: 8 threads/row
    const int q8 = t & 7;
    const int col = wv * 16 + l15;

    // per-type routing + per-lane constants (static indices only; dynamic select via ternary)
    int stIdx4[4];
#pragma unroll
    for (int s = 0; s < 4; ++s) stIdx4[s] = s * 4 + best_t_for(tm, s, nullptr);
    float b1vA[4], b2vA[4], c1vA[4], c2wA[4];
#pragma unroll
    for (int s = 0; s < 4; ++s) {
        b1vA[s] = b1g[stIdx4[s] * 128 + col];
        b2vA[s] = b2g[stIdx4[s] * 128 + col];
        c1vA[s] = c1g[stIdx4[s] * 128 + col];
        c2wA[s] = C2[stIdx4[s] * 128 + col];
    }
    if (t < 4) c2sL[t] = c2[stIdx4[t]];

    // ---- stage A: dense rows -> swizzled bf16 LDS ----
    {
        const int g = gid0 + myRow;
        const float4* sp = (const float4*)(states + (size_t)g * 128 + q8 * 16);
        float4 v[4];
#pragma unroll
        for (int i = 0; i < 4; ++i) v[i] = sp[i];
        unsigned short* dstRow = &Abuf[myRow * 128];
        const int rot = (myRow & 15) << 3;
#pragma unroll
        for (int i = 0; i < 4; ++i) {
            int c = (q8 * 16 + i * 4 + rot) & 127;
            ushort4 o;
            o.x = f2bf(v[i].x); o.y = f2bf(v[i].y);
            o.z = f2bf(v[i].z); o.w = f2bf(v[i].w);
            *(ushort4*)(dstRow + c) = o;
        }
    }

    // ---- wave 0: types, prob, scores, local ballot-partition ----
    if (t < 64) {
        int ty = type_ids[gid0 + t];
        scoreLds[t] = scores[gid0 + t];
        float m = tm[ty * 4];
#pragma unroll
        for (int j = 1; j < 4; ++j) m = fmaxf(m, tm[ty * 4 + j]);
        out_prob[gid0 + t] = 1.f / (1.f + expf(-m));

        unsigned long long m0 = __ballot(ty == 0);
        unsigned long long m1 = __ballot(ty == 1);
        unsigned long long m2 = __ballot(ty == 2);
        unsigned long long m3 = __ballot(ty == 3);
        int c0 = (int)__popcll(m0), c1 = (int)__popcll(m1);
        int c2_ = (int)__popcll(m2), c3 = (int)__popcll(m3);
        int ns0 = (c0 + 15) >> 4, ns1 = (c1 + 15) >> 4;
        int ns2 = (c2_ + 15) >> 4, ns3 = (c3 + 15) >> 4;
        int pb1 = ns0 * 16, pb2 = pb1 + ns1 * 16, pb3 = pb2 + ns2 * 16;
        // init pads (same-wave DS ops are ordered: inits precede the scatter below)
        permLds[t] = -1;
        if (t < 48) permLds[64 + t] = -1;
        unsigned long long lt = (1ull << t) - 1ull;
        int pb = (ty == 0) ? 0 : (ty == 1) ? pb1 : (ty == 2) ? pb2 : pb3;
        unsigned long long mm = (ty == 0) ? m0 : (ty == 1) ? m1 : (ty == 2) ? m2 : m3;
        permLds[pb + (int)__popcll(mm & lt)] = t;
        if (t < 8) {
            int st = (t < ns0) ? 0 : (t < ns0 + ns1) ? 1 : (t < ns0 + ns1 + ns2) ? 2 : 3;
            segTypeLds[t] = st;
        }
        if (t == 0) Gs = ns0 + ns1 + ns2 + ns3;
    }
    __syncthreads();
    const int G = Gs;   // 4..7

    const unsigned short* __restrict__ wbase = wbf;
    // load one (type, matrix) fragment set for this wave's 16-col slice: 32 VGPRs
    auto loadWf = [&](int m, int sty, s16x8 wf[4]) {
        const unsigned short* wb = wbase + ((size_t)sty * 3 + m) * 16384;
#pragma unroll
        for (int kk = 0; kk < 4; ++kk)
            wf[kk] = *(const s16x8*)(wb + (size_t)((kk * 8 + wv) * 64 + lane) * 8);
    };
    // gemm over permuted A rows of segment g (pad lanes -> zero fragment)
    auto gemmA = [&](int g, const s16x8 wf[4]) -> f32x4 {
        f32x4 acc = {0.f, 0.f, 0.f, 0.f};
        int pRow = permLds[g * 16 + l15];
        int rbase = ((pRow >= 0) ? pRow : 0) * 128;
        int rot = (pRow & 15) << 3;
#pragma unroll
        for (int kk = 0; kk < 4; ++kk) {
            s16x8 af = *(const s16x8*)(Abuf + rbase + ((kk * 32 + quad * 8 + rot) & 127));
            if (pRow < 0) af = s16x8{0, 0, 0, 0, 0, 0, 0, 0};
            acc = __builtin_amdgcn_mfma_f32_16x16x32_bf16(af, wf[kk], acc, 0, 0, 0);
        }
        return acc;
    };
    // gemm over dense Hbuf rows of segment g
    auto gemmH = [&](int g, const s16x8 wf[4]) -> f32x4 {
        f32x4 acc = {0.f, 0.f, 0.f, 0.f};
        const unsigned short* hb = Hbuf + (g * 16 + l15) * 128;
#pragma unroll
        for (int kk = 0; kk < 4; ++kk) {
            s16x8 af = *(const s16x8*)(hb + ((kk * 32 + quad * 8 + (l15 << 3)) & 127));
            acc = __builtin_amdgcn_mfma_f32_16x16x32_bf16(af, wf[kk], acc, 0, 0, 0);
        }
        return acc;
    };

    s16x8 wfP[2][4];

    // ---- phase 1: h = relu(A@W1 + b1) -> Hbuf (per segment, W1 ping-pong) ----
    loadWf(0, segTypeLds[0], wfP[0]);
#pragma unroll
    for (int g = 0; g < 7; ++g) {
        if (g < G) {
            if (g + 1 < G) loadWf(0, segTypeLds[g + 1], wfP[(g + 1) & 1]);
            f32x4 a = gemmA(g, wfP[g & 1]);
            int sty = segTypeLds[g];
            float bb = (sty == 0) ? b1vA[0] : (sty == 1) ? b1vA[1] : (sty == 2) ? b1vA[2] : b1vA[3];
#pragma unroll
            for (int r = 0; r < 4; ++r) {
                int row = g * 16 + quad * 4 + r;
                float v = fmaxf(a[r] + bb, 0.f);
                Hbuf[row * 128 + ((col + ((row & 15) << 3)) & 127)] = f2bf(v);
            }
        }
    }
    __syncthreads();

    // ---- phase 2: y = h@W2 + b2 -> out_state (per segment, W2 ping-pong) ----
    loadWf(1, segTypeLds[0], wfP[0]);
#pragma unroll
    for (int g = 0; g < 7; ++g) {
        if (g < G) {
            if (g + 1 < G) loadWf(1, segTypeLds[g + 1], wfP[(g + 1) & 1]);
            f32x4 a = gemmH(g, wfP[g & 1]);
            int sty = segTypeLds[g];
            float bb = (sty == 0) ? b2vA[0] : (sty == 1) ? b2vA[1] : (sty == 2) ? b2vA[2] : b2vA[3];
#pragma unroll
            for (int r = 0; r < 4; ++r) {
                int p = permLds[g * 16 + quad * 4 + r];
                if (p >= 0) out_state[(size_t)(gid0 + p) * 128 + col] = a[r] + bb;
            }
        }
    }

    // ---- phase 3: classifier partials (per segment, C1 ping-pong) ----
    loadWf(2, segTypeLds[0], wfP[0]);
#pragma unroll
    for (int g = 0; g < 7; ++g) {
        if (g < G) {
            if (g + 1 < G) loadWf(2, segTypeLds[g + 1], wfP[(g + 1) & 1]);
            f32x4 a = gemmA(g, wfP[g & 1]);
            int sty = segTypeLds[g];
            float cv = (sty == 0) ? c1vA[0] : (sty == 1) ? c1vA[1] : (sty == 2) ? c1vA[2] : c1vA[3];
            float cw = (sty == 0) ? c2wA[0] : (sty == 1) ? c2wA[1] : (sty == 2) ? c2wA[2] : c2wA[3];
            float part[4];
#pragma unroll
            for (int r = 0; r < 4; ++r) part[r] = fmaxf(a[r] + cv, 0.f) * cw;
#pragma unroll
            for (int off = 1; off < 16; off <<= 1)
#pragma unroll
                for (int r = 0; r < 4; ++r) part[r] += __shfl_xor(part[r], off, 64);
            if (l15 == 0) {
#pragma unroll
                for (int r = 0; r < 4; ++r) pLds[wv][g * 16 + quad * 4 + r] = part[r];
            }
        }
    }
    __syncthreads();

    // ---- epilogue: per padded slot, cross-wave sum, sigmoid, min, store ----
    if (t < 112 && t < G * 16) {
        int p = permLds[t];
        if (p >= 0) {
            float tot = pLds[0][t] + pLds[1][t] + pLds[2][t] + pLds[3][t]
                      + pLds[4][t] + pLds[5][t] + pLds[6][t] + pLds[7][t]
                      + c2sL[segTypeLds[t >> 4]];
            float cls = 1.f / (1.f + expf(-tot));
            out_score[gid0 + p] = fminf(scoreLds[p], cls);
        }
    }
}

extern "C" void kernel_launch(void* const* d_in, const int* in_sizes, int n_in,
                              void* d_out, int out_size, void* d_ws, size_t ws_size,
                              hipStream_t stream) {
    const float* states = (const float*)d_in[0];
    const float* scores = (const float*)d_in[1];
    const int*   type_ids = (const int*)d_in[2];
    const float* tm = (const float*)d_in[3];
    const float* W1 = (const float*)d_in[4];
    const float* b1 = (const float*)d_in[5];
    const float* W2 = (const float*)d_in[6];
    const float* b2 = (const float*)d_in[7];
    const float* C1 = (const float*)d_in[8];
    const float* c1 = (const float*)d_in[9];
    const float* C2 = (const float*)d_in[10];
    const float* c2 = (const float*)d_in[11];

    unsigned short* wbf = (unsigned short*)d_ws;            // 12 * 16384 bf16, frag-linear

    float* out_state = (float*)d_out;                       // N*128
    float* out_score = out_state + (size_t)Nn * 128;        // N
    float* out_prob  = out_score + Nn;                      // N

    k_prepw<<<96, 256, 0, stream>>>(tm, W1, W2, C1, wbf);
    k_fused<<<1024, 512, 0, stream>>>(states, scores, type_ids, tm, b1, b2, c1,
        C2, c2, wbf, out_state, out_score, out_prob);
}

// Round 6
// 128.602 us; speedup vs baseline: 1.0582x; 1.0582x over previous
//
#include <hip/hip_runtime.h>
#include <math.h>

#define Nn 65536

typedef short s16x8 __attribute__((ext_vector_type(8)));
typedef float f32x4 __attribute__((ext_vector_type(4)));
typedef unsigned int u32;

__device__ __forceinline__ unsigned short f2bf(float x) {
    u32 u = __float_as_uint(x);
    u += 0x7FFFu + ((u >> 16) & 1u);
    return (unsigned short)(u >> 16);
}

// argmax over row s of the 4x4 type_matching (first max wins, matches jnp.argmax)
__device__ __forceinline__ int best_t_for(const float* __restrict__ tm, int s, float* mOut) {
    float m = tm[s * 4];
    int am = 0;
#pragma unroll
    for (int j = 1; j < 4; ++j) {
        float v = tm[s * 4 + j];
        if (v > m) { m = v; am = j; }
    }
    if (mOut) *mOut = m;
    return am;
}

// ============ k_prepw: weight convert ONLY (96 blocks) ============
// fp32 [D][H] -> bf16 fragment-linear for the 12 live (s, best_t) matrices
__global__ void k_prepw(const float* __restrict__ tm,
                        const float* __restrict__ W1, const float* __restrict__ W2,
                        const float* __restrict__ C1, unsigned short* __restrict__ wbf) {
    int u = blockIdx.x * 256 + threadIdx.x;      // 0..24575
    int mat = u >> 11;
    int rr = u & 2047;
    int f = rr >> 6, lane = rr & 63;
    int kk = f >> 3, n8 = f & 7;
    int q = lane >> 4, l15 = lane & 15;
    int sm = mat / 3, w = mat - sm * 3;
    int t = best_t_for(tm, sm, nullptr);
    const float* src = (w == 0) ? W1 : (w == 1) ? W2 : C1;
    const float* sp = src + (((sm * 4 + t) << 14) + n8 * 16 + l15);
    int k0 = kk * 32 + q * 8;
    s16x8 o;
#pragma unroll
    for (int j = 0; j < 8; ++j) o[j] = (short)f2bf(sp[(k0 + j) * 128]);
    *(s16x8*)(wbf + (size_t)u * 8) = o;
}

// ================= k_fused: M=128 rows/block, per-type phase grouping =================
// Round-5 lesson: 64-row blocks forced per-segment weight reloads -> ~560 MB of L2 traffic.
// Weight traffic = (weight bytes/block) x nblocks. Fix: M=128 (512 blocks, 8 waves x 16
// cols), and group the segment loop BY TYPE so each (type,matrix) fragment set loads once
// per block-phase: 12 sets x 4 KB/wave -> ~200 MB total, with only 16 VGPRs resident.
// 512 blocks x 8 waves = 4096 waves = exactly one 16-wave/CU generation (2 blocks/CU,
// LDS 77.4 KB). Local 2-wave ballot partition into <=11 type-uniform 16-row segments.
// Classifier partials accumulate via LDS float atomics into pSum[176] (704 B).
// A/H swizzle: row*128 + ((col + (row&15)*8) & 127)
__global__ __launch_bounds__(512, 4) void k_fused(
    const float* __restrict__ states, const float* __restrict__ scores,
    const int* __restrict__ type_ids, const float* __restrict__ tm,
    const float* __restrict__ b1g, const float* __restrict__ b2g,
    const float* __restrict__ c1g, const float* __restrict__ C2,
    const float* __restrict__ c2, const unsigned short* __restrict__ wbf,
    float* __restrict__ out_state, float* __restrict__ out_score,
    float* __restrict__ out_prob)
{
    __shared__ __align__(16) unsigned short Abuf[128 * 128];   // 32 KB
    __shared__ __align__(16) unsigned short Hbuf[176 * 128];   // 44 KB (11 segs max)
    __shared__ int permLds[176];                               // 704 B
    __shared__ float pSum[176];                                // 704 B
    __shared__ int wcnt[2][4];                                 // 32 B

    const int t = threadIdx.x;
    const int gid0 = blockIdx.x * 128;
    const int lane = t & 63;
    const int wv = t >> 6;            // wave 0..7 -> 16-col slice
    const int l15 = lane & 15;
    const int quad = lane >> 4;
    const int myRow = t >> 2;         // staging: 4 threads/row, 128 rows
    const int q4 = t & 3;
    const int col = wv * 16 + l15;

    // routing (all threads; 16 broadcast-cached scalar loads)
    int stIdx4[4];
    float bmax[4];
#pragma unroll
    for (int s = 0; s < 4; ++s) stIdx4[s] = s * 4 + best_t_for(tm, s, &bmax[s]);

    if (t < 176) { permLds[t] = -1; pSum[t] = 0.f; }

    // ---- stage A: 128 dense rows -> swizzled bf16 LDS ----
    {
        const int g = gid0 + myRow;
        const float4* sp = (const float4*)(states + (size_t)g * 128 + q4 * 32);
        float4 v[8];
#pragma unroll
        for (int i = 0; i < 8; ++i) v[i] = sp[i];
        unsigned short* dstRow = &Abuf[myRow * 128];
        const int rot = (myRow & 15) << 3;
#pragma unroll
        for (int i = 0; i < 8; ++i) {
            int c = (q4 * 32 + i * 4 + rot) & 127;
            ushort4 o;
            o.x = f2bf(v[i].x); o.y = f2bf(v[i].y);
            o.z = f2bf(v[i].z); o.w = f2bf(v[i].w);
            *(ushort4*)(dstRow + c) = o;
        }
    }

    // ---- partition: waves 0,1 ballot their 64 rows ----
    int myty = 0, w2 = 0;
    unsigned long long msk = 0;
    if (t < 128) {
        w2 = t >> 6;
        myty = type_ids[gid0 + t];
#pragma unroll
        for (int sv = 0; sv < 4; ++sv) {
            unsigned long long mm = __ballot(myty == sv);
            if (myty == sv) msk = mm;
            if (lane == 0) wcnt[w2][sv] = (int)__popcll(mm);
        }
    }
    __syncthreads();   // B1: wcnt + Abuf + perm-init visible

    // segment layout (redundant scalar compute in every thread)
    int nsA[4], sbA[4], G;
    {
        int sb = 0;
#pragma unroll
        for (int sv = 0; sv < 4; ++sv) {
            int c = wcnt[0][sv] + wcnt[1][sv];
            nsA[sv] = (c + 15) >> 4;
            sbA[sv] = sb;
            sb += nsA[sv];
        }
        G = sb;   // 4..11 segments
    }
    if (t < 128) {
        unsigned long long lt = (1ull << lane) - 1ull;
        int pos = sbA[myty] * 16 + ((w2 == 1) ? wcnt[0][myty] : 0) + (int)__popcll(msk & lt);
        permLds[pos] = t;
    }
    __syncthreads();   // B2: perm ready

    const unsigned short* __restrict__ wbase = wbf;
    s16x8 wf[4];
    // load (type, matrix) fragment set for this wave's 16-col slice: 16 VGPRs
    auto loadWf = [&](int ty, int m) {
        const unsigned short* wb = wbase + ((size_t)ty * 3 + m) * 16384;
#pragma unroll
        for (int kk = 0; kk < 4; ++kk)
            wf[kk] = *(const s16x8*)(wb + (size_t)((kk * 8 + wv) * 64 + lane) * 8);
    };
    // gemm over permuted A rows of segment seg (pad lanes read row 0 -> discarded later)
    auto gemmA = [&](int seg) -> f32x4 {
        f32x4 acc = {0.f, 0.f, 0.f, 0.f};
        int pRow = permLds[seg * 16 + l15];
        int rr = (pRow >= 0) ? pRow : 0;
        const int rbase = rr * 128;
        const int rot = (rr & 15) << 3;
#pragma unroll
        for (int kk = 0; kk < 4; ++kk) {
            s16x8 af = *(const s16x8*)(Abuf + rbase + ((kk * 32 + quad * 8 + rot) & 127));
            acc = __builtin_amdgcn_mfma_f32_16x16x32_bf16(af, wf[kk], acc, 0, 0, 0);
        }
        return acc;
    };
    // gemm over dense Hbuf rows of segment seg
    auto gemmH = [&](int seg) -> f32x4 {
        f32x4 acc = {0.f, 0.f, 0.f, 0.f};
        const unsigned short* hb = Hbuf + (seg * 16 + l15) * 128;
#pragma unroll
        for (int kk = 0; kk < 4; ++kk) {
            s16x8 af = *(const s16x8*)(hb + ((kk * 32 + quad * 8 + (l15 << 3)) & 127));
            acc = __builtin_amdgcn_mfma_f32_16x16x32_bf16(af, wf[kk], acc, 0, 0, 0);
        }
        return acc;
    };

    // ---- per-type phase groups: weights load once per (type, matrix) ----
    for (int ty = 0; ty < 4; ++ty) {
        const int ns = nsA[ty];
        if (ns == 0) continue;                 // uniform across block
        const int sb = sbA[ty];
        const int si0 = stIdx4[ty];

        // phase 1: h = relu(A@W1 + b1) -> Hbuf
        loadWf(ty, 0);
        {
            const float b1v = b1g[si0 * 128 + col];
            for (int si = 0; si < ns; ++si) {
                const int seg = sb + si;
                f32x4 a = gemmA(seg);
#pragma unroll
                for (int r = 0; r < 4; ++r) {
                    int row = seg * 16 + quad * 4 + r;
                    float v = fmaxf(a[r] + b1v, 0.f);
                    Hbuf[row * 128 + ((col + ((row & 15) << 3)) & 127)] = f2bf(v);
                }
            }
        }
        __syncthreads();   // this type's Hbuf segments complete (block-uniform)

        // phase 2: y = h@W2 + b2 -> out_state scatter
        loadWf(ty, 1);
        {
            const float b2v = b2g[si0 * 128 + col];
            for (int si = 0; si < ns; ++si) {
                const int seg = sb + si;
                f32x4 a = gemmH(seg);
#pragma unroll
                for (int r = 0; r < 4; ++r) {
                    int p = permLds[seg * 16 + quad * 4 + r];
                    if (p >= 0) out_state[(size_t)(gid0 + p) * 128 + col] = a[r] + b2v;
                }
            }
        }

        // phase 3: classifier partials -> pSum (LDS float atomics)
        loadWf(ty, 2);
        {
            const float c1v = c1g[si0 * 128 + col];
            const float c2w = C2[si0 * 128 + col];
            for (int si = 0; si < ns; ++si) {
                const int seg = sb + si;
                f32x4 a = gemmA(seg);
                float part[4];
#pragma unroll
                for (int r = 0; r < 4; ++r) part[r] = fmaxf(a[r] + c1v, 0.f) * c2w;
#pragma unroll
                for (int off = 1; off < 16; off <<= 1)
#pragma unroll
                    for (int r = 0; r < 4; ++r)
                        part[r] += __shfl_xor(part[r], off, 64);
                if (l15 == 0) {
#pragma unroll
                    for (int r = 0; r < 4; ++r)
                        atomicAdd(&pSum[seg * 16 + quad * 4 + r], part[r]);
                }
            }
        }
    }
    __syncthreads();   // all pSum contributions done

    // ---- epilogue: sigmoid, min, score + prob stores ----
    if (t < G * 16) {
        int p = permLds[t];
        if (p >= 0) {
            int seg = t >> 4;
            int sty = (seg >= sbA[1] ? 1 : 0) + (seg >= sbA[2] ? 1 : 0) + (seg >= sbA[3] ? 1 : 0);
            float tot = pSum[t] + c2[stIdx4[sty]];
            float cls = 1.f / (1.f + expf(-tot));
            out_score[gid0 + p] = fminf(scores[gid0 + p], cls);
            out_prob[gid0 + p] = 1.f / (1.f + expf(-bmax[sty]));
        }
    }
}

extern "C" void kernel_launch(void* const* d_in, const int* in_sizes, int n_in,
                              void* d_out, int out_size, void* d_ws, size_t ws_size,
                              hipStream_t stream) {
    const float* states = (const float*)d_in[0];
    const float* scores = (const float*)d_in[1];
    const int*   type_ids = (const int*)d_in[2];
    const float* tm = (const float*)d_in[3];
    const float* W1 = (const float*)d_in[4];
    const float* b1 = (const float*)d_in[5];
    const float* W2 = (const float*)d_in[6];
    const float* b2 = (const float*)d_in[7];
    const float* C1 = (const float*)d_in[8];
    const float* c1 = (const float*)d_in[9];
    const float* C2 = (const float*)d_in[10];
    const float* c2 = (const float*)d_in[11];

    unsigned short* wbf = (unsigned short*)d_ws;            // 12 * 16384 bf16, frag-linear

    float* out_state = (float*)d_out;                       // N*128
    float* out_score = out_state + (size_t)Nn * 128;        // N
    float* out_prob  = out_score + Nn;                      // N

    k_prepw<<<96, 256, 0, stream>>>(tm, W1, W2, C1, wbf);
    k_fused<<<512, 512, 0, stream>>>(states, scores, type_ids, tm, b1, b2, c1,
        C2, c2, wbf, out_state, out_score, out_prob);
}